// Round 1
// baseline (583.855 us; speedup 1.0000x reference)
//
#include <hip/hip_runtime.h>
#include <hip/hip_bf16.h>

#define SLEN 4096
#define DH 768
#define NHEAD 12
#define DA 64

using short8 = __attribute__((ext_vector_type(8))) short;
using f32x4  = __attribute__((ext_vector_type(4))) float;

static __device__ __forceinline__ unsigned short f2b(float f) {
    union { float f; unsigned u; } x; x.f = f;
    unsigned r = (x.u + 0x7FFFu + ((x.u >> 16) & 1)) >> 16;
    return (unsigned short)r;
}

// ---------------- weight transpose + bf16 convert: Wt[n][k] = bf16(W[k][n]) ----
__global__ __launch_bounds__(256) void wtrans(const float* __restrict__ W,
                                              unsigned short* __restrict__ Wt) {
    __shared__ float tile[64][65];
    const int t = threadIdx.x;
    const int tk = blockIdx.x / 12, tn = blockIdx.x % 12;
    const int k0 = tk * 64, n0 = tn * 64;
#pragma unroll
    for (int i = 0; i < 4; ++i) {
        int uid = t + 256 * i;
        int r = uid >> 4, c = (uid & 15) * 4;
        float4 v4 = *reinterpret_cast<const float4*>(W + (size_t)(k0 + r) * DH + n0 + c);
        tile[r][c] = v4.x; tile[r][c + 1] = v4.y; tile[r][c + 2] = v4.z; tile[r][c + 3] = v4.w;
    }
    __syncthreads();
#pragma unroll
    for (int i = 0; i < 2; ++i) {
        int uid = t + 256 * i;
        int n = uid >> 3, c = (uid & 7) * 8;
        union { unsigned short us[8]; uint4 u; } pk;
#pragma unroll
        for (int j = 0; j < 8; ++j) pk.us[j] = f2b(tile[c + j][n]);
        *reinterpret_cast<uint4*>(Wt + (size_t)(n0 + n) * DH + k0 + c) = pk.u;
    }
}

// ---------------- QKV projection: Y(head-split bf16) = bf16(X fp32) @ Wt^T ----
__global__ __launch_bounds__(256) void proj_qkv(const float* __restrict__ X,
                                                const unsigned short* __restrict__ Wt,
                                                unsigned short* __restrict__ Y) {
    __shared__ unsigned short As[128][40];  // +8 pad: 2-way bank aliasing only
    __shared__ unsigned short Bs[64][40];
    const int t = threadIdx.x;
    const int w = t >> 6, lane = t & 63, lr = lane & 15, lg = lane >> 4;
    const int row0 = blockIdx.x * 128;
    const int h = blockIdx.y;
    const int n0 = h * 64;
    f32x4 acc[2][4] = {};
    for (int kt = 0; kt < 24; ++kt) {
        const int k0 = kt * 32;
#pragma unroll
        for (int i = 0; i < 4; ++i) {   // stage A: fp32 -> bf16
            int r = (t >> 3) + 32 * i;
            int c = (t & 7) * 4;
            float4 v4 = *reinterpret_cast<const float4*>(X + (size_t)(row0 + r) * DH + k0 + c);
            uint2 pk;
            pk.x = (unsigned)f2b(v4.x) | ((unsigned)f2b(v4.y) << 16);
            pk.y = (unsigned)f2b(v4.z) | ((unsigned)f2b(v4.w) << 16);
            *reinterpret_cast<uint2*>(&As[r][c]) = pk;
        }
        {   // stage B: bf16 16B chunks
            int n = t >> 2, c = (t & 3) * 8;
            *reinterpret_cast<uint4*>(&Bs[n][c]) =
                *reinterpret_cast<const uint4*>(Wt + (size_t)(n0 + n) * DH + k0 + c);
        }
        __syncthreads();
        short8 af[2], bf[4];
#pragma unroll
        for (int mi = 0; mi < 2; ++mi)
            af[mi] = *reinterpret_cast<const short8*>(&As[w * 32 + mi * 16 + lr][lg * 8]);
#pragma unroll
        for (int ni = 0; ni < 4; ++ni)
            bf[ni] = *reinterpret_cast<const short8*>(&Bs[ni * 16 + lr][lg * 8]);
#pragma unroll
        for (int mi = 0; mi < 2; ++mi)
#pragma unroll
            for (int ni = 0; ni < 4; ++ni)
                acc[mi][ni] = __builtin_amdgcn_mfma_f32_16x16x32_bf16(af[mi], bf[ni], acc[mi][ni], 0, 0, 0);
        __syncthreads();
    }
#pragma unroll
    for (int mi = 0; mi < 2; ++mi)
#pragma unroll
        for (int ni = 0; ni < 4; ++ni)
#pragma unroll
            for (int r = 0; r < 4; ++r) {
                int row = row0 + w * 32 + mi * 16 + lg * 4 + r;
                int b = row >> 12, s = row & 4095;
                int d = ni * 16 + lr;
                Y[(size_t)((b * NHEAD + h) * SLEN + s) * DA + d] = f2b(acc[mi][ni][r]);
            }
}

// ---------------- flash attention ----
__global__ __launch_bounds__(256) void attn_kernel(const unsigned short* __restrict__ Qh,
                                                   const unsigned short* __restrict__ Kh,
                                                   const unsigned short* __restrict__ Vh,
                                                   const int* __restrict__ mask,
                                                   unsigned short* __restrict__ AT) {
    __shared__ unsigned short Ks[64][72];
    __shared__ unsigned short Vt[64][72];
    __shared__ unsigned short Pl[4][16][72];
    __shared__ float biasb[64];
    const int t = threadIdx.x;
    const int w = t >> 6, lane = t & 63, lr = lane & 15, lg = lane >> 4;
    const int q0 = blockIdx.x * 64;
    const int bh = blockIdx.y;
    const int b = bh / NHEAD, h = bh % NHEAD;
    const size_t base = (size_t)bh * SLEN * DA;

    short8 qf[2];
#pragma unroll
    for (int ks = 0; ks < 2; ++ks)
        qf[ks] = *reinterpret_cast<const short8*>(Qh + base + (size_t)(q0 + w * 16 + lr) * DA + ks * 32 + lg * 8);

    float m_run[4], l_run[4];
    f32x4 oacc[4] = {};
#pragma unroll
    for (int r = 0; r < 4; ++r) { m_run[r] = -1e30f; l_run[r] = 0.f; }

    for (int kt = 0; kt < 64; ++kt) {
        const int kk0 = kt * 64;
#pragma unroll
        for (int i = 0; i < 2; ++i) {  // stage K row-major, V transposed
            int uid = t + 256 * i;
            int r = uid >> 3, c = (uid & 7) * 8;
            *reinterpret_cast<uint4*>(&Ks[r][c]) =
                *reinterpret_cast<const uint4*>(Kh + base + (size_t)(kk0 + r) * DA + c);
            union { uint4 u; unsigned short us[8]; } vv;
            vv.u = *reinterpret_cast<const uint4*>(Vh + base + (size_t)(kk0 + r) * DA + c);
#pragma unroll
            for (int j = 0; j < 8; ++j) Vt[c + j][r] = vv.us[j];
        }
        if (t < 64) biasb[t] = -1e9f * (float)mask[b * SLEN + kk0 + t];
        __syncthreads();

        // S = Q K^T   (row = q within wave band, col = key)
        f32x4 s[4] = {};
#pragma unroll
        for (int ks = 0; ks < 2; ++ks)
#pragma unroll
            for (int ni = 0; ni < 4; ++ni) {
                short8 bfr = *reinterpret_cast<const short8*>(&Ks[ni * 16 + lr][ks * 32 + lg * 8]);
                s[ni] = __builtin_amdgcn_mfma_f32_16x16x32_bf16(qf[ks], bfr, s[ni], 0, 0, 0);
            }
        float bs[4];
#pragma unroll
        for (int ni = 0; ni < 4; ++ni) bs[ni] = biasb[ni * 16 + lr];

        unsigned short pb[4][4];
#pragma unroll
        for (int r = 0; r < 4; ++r) {
            float sv[4];
            float rmax = -1e30f;
#pragma unroll
            for (int ni = 0; ni < 4; ++ni) { sv[ni] = s[ni][r] * 0.125f + bs[ni]; rmax = fmaxf(rmax, sv[ni]); }
#pragma unroll
            for (int off = 1; off < 16; off <<= 1) rmax = fmaxf(rmax, __shfl_xor(rmax, off));
            float m_new = fmaxf(m_run[r], rmax);
            float sc = __expf(m_run[r] - m_new);
            float psum = 0.f;
#pragma unroll
            for (int ni = 0; ni < 4; ++ni) {
                float p = __expf(sv[ni] - m_new);
                pb[ni][r] = f2b(p);
                psum += p;
            }
#pragma unroll
            for (int off = 1; off < 16; off <<= 1) psum += __shfl_xor(psum, off);
            l_run[r] = l_run[r] * sc + psum;
            m_run[r] = m_new;
#pragma unroll
            for (int ni = 0; ni < 4; ++ni) oacc[ni][r] *= sc;
        }
        // P -> LDS (per-wave band; same-wave DS ops are in-order, no barrier needed)
#pragma unroll
        for (int ni = 0; ni < 4; ++ni)
#pragma unroll
            for (int r = 0; r < 4; ++r)
                Pl[w][lg * 4 + r][ni * 16 + lr] = pb[ni][r];
        // O += P V
#pragma unroll
        for (int ks = 0; ks < 2; ++ks) {
            short8 af = *reinterpret_cast<const short8*>(&Pl[w][lr][ks * 32 + lg * 8]);
#pragma unroll
            for (int ni = 0; ni < 4; ++ni) {
                short8 bv = *reinterpret_cast<const short8*>(&Vt[ni * 16 + lr][ks * 32 + lg * 8]);
                oacc[ni] = __builtin_amdgcn_mfma_f32_16x16x32_bf16(af, bv, oacc[ni], 0, 0, 0);
            }
        }
        __syncthreads();
    }
#pragma unroll
    for (int ni = 0; ni < 4; ++ni)
#pragma unroll
        for (int r = 0; r < 4; ++r) {
            int qrow = q0 + w * 16 + lg * 4 + r;
            int d = ni * 16 + lr;
            float val = oacc[ni][r] / l_run[r];
            AT[(size_t)(b * SLEN + qrow) * DH + h * DA + d] = f2b(val);
        }
}

// ---------------- output projection: out(fp32) = AT(bf16) @ Wt_o^T + b_o ----
__global__ __launch_bounds__(256) void proj_out(const unsigned short* __restrict__ X,
                                                const unsigned short* __restrict__ Wt,
                                                const float* __restrict__ bias,
                                                float* __restrict__ Y) {
    __shared__ unsigned short As[128][40];
    __shared__ unsigned short Bs[64][40];
    const int t = threadIdx.x;
    const int w = t >> 6, lane = t & 63, lr = lane & 15, lg = lane >> 4;
    const int row0 = blockIdx.x * 128;
    const int n0 = blockIdx.y * 64;
    f32x4 acc[2][4] = {};
    for (int kt = 0; kt < 24; ++kt) {
        const int k0 = kt * 32;
#pragma unroll
        for (int i = 0; i < 2; ++i) {
            int uid = t + 256 * i;
            int r = uid >> 2, c = (uid & 3) * 8;
            *reinterpret_cast<uint4*>(&As[r][c]) =
                *reinterpret_cast<const uint4*>(X + (size_t)(row0 + r) * DH + k0 + c);
        }
        {
            int n = t >> 2, c = (t & 3) * 8;
            *reinterpret_cast<uint4*>(&Bs[n][c]) =
                *reinterpret_cast<const uint4*>(Wt + (size_t)(n0 + n) * DH + k0 + c);
        }
        __syncthreads();
        short8 af[2], bf[4];
#pragma unroll
        for (int mi = 0; mi < 2; ++mi)
            af[mi] = *reinterpret_cast<const short8*>(&As[w * 32 + mi * 16 + lr][lg * 8]);
#pragma unroll
        for (int ni = 0; ni < 4; ++ni)
            bf[ni] = *reinterpret_cast<const short8*>(&Bs[ni * 16 + lr][lg * 8]);
#pragma unroll
        for (int mi = 0; mi < 2; ++mi)
#pragma unroll
            for (int ni = 0; ni < 4; ++ni)
                acc[mi][ni] = __builtin_amdgcn_mfma_f32_16x16x32_bf16(af[mi], bf[ni], acc[mi][ni], 0, 0, 0);
        __syncthreads();
    }
#pragma unroll
    for (int ni = 0; ni < 4; ++ni) {
        float bv = bias[n0 + ni * 16 + lr];
#pragma unroll
        for (int mi = 0; mi < 2; ++mi)
#pragma unroll
            for (int r = 0; r < 4; ++r) {
                int row = row0 + w * 32 + mi * 16 + lg * 4 + r;
                Y[(size_t)row * DH + n0 + ni * 16 + lr] = acc[mi][ni][r] + bv;
            }
    }
}

extern "C" void kernel_launch(void* const* d_in, const int* in_sizes, int n_in,
                              void* d_out, int out_size, void* d_ws, size_t ws_size,
                              hipStream_t stream) {
    const float* v   = (const float*)d_in[0];
    const float* k   = (const float*)d_in[1];
    const float* q   = (const float*)d_in[2];
    const int*  mask = (const int*)d_in[3];
    const float* w_v = (const float*)d_in[4];
    const float* w_k = (const float*)d_in[5];
    const float* w_q = (const float*)d_in[6];
    const float* w_o = (const float*)d_in[7];
    const float* b_o = (const float*)d_in[8];
    float* out = (float*)d_out;

    char* ws = (char*)d_ws;
    unsigned short* Qh  = (unsigned short*)(ws);                 // 12.58 MB each
    unsigned short* Kh  = (unsigned short*)(ws + 12582912);
    unsigned short* Vh  = (unsigned short*)(ws + 25165824);
    unsigned short* AT  = (unsigned short*)(ws + 37748736);
    unsigned short* WtV = (unsigned short*)(ws + 50331648);      // 1.18 MB each
    unsigned short* WtK = WtV + 589824;
    unsigned short* WtQ = WtK + 589824;
    unsigned short* WtO = WtQ + 589824;

    wtrans<<<144, 256, 0, stream>>>(w_v, WtV);
    wtrans<<<144, 256, 0, stream>>>(w_k, WtK);
    wtrans<<<144, 256, 0, stream>>>(w_q, WtQ);
    wtrans<<<144, 256, 0, stream>>>(w_o, WtO);
    proj_qkv<<<dim3(64, 12), 256, 0, stream>>>(v, WtV, Vh);
    proj_qkv<<<dim3(64, 12), 256, 0, stream>>>(k, WtK, Kh);
    proj_qkv<<<dim3(64, 12), 256, 0, stream>>>(q, WtQ, Qh);
    attn_kernel<<<dim3(64, 24), 256, 0, stream>>>(Qh, Kh, Vh, mask, AT);
    proj_out<<<dim3(64, 12), 256, 0, stream>>>(AT, WtO, b_o, out);
}

// Round 2
// 294.652 us; speedup vs baseline: 1.9815x; 1.9815x over previous
//
#include <hip/hip_runtime.h>
#include <hip/hip_bf16.h>

#define SLEN 4096
#define DH 768
#define NHEAD 12
#define DA 64

using short8 = __attribute__((ext_vector_type(8))) short;
using f32x4  = __attribute__((ext_vector_type(4))) float;

static __device__ __forceinline__ unsigned short f2b(float f) {
    union { float f; unsigned u; } x; x.f = f;
    unsigned r = (x.u + 0x7FFFu + ((x.u >> 16) & 1)) >> 16;
    return (unsigned short)r;
}

static __device__ __forceinline__ unsigned pkbf(float a, float b) {
    __hip_bfloat162 h = __float22bfloat162_rn(float2{a, b});
    union { __hip_bfloat162 h; unsigned u; } c; c.h = h; return c.u;
}

#define GLD_LDS16(gp, lp) __builtin_amdgcn_global_load_lds( \
    (const __attribute__((address_space(1))) unsigned int*)(gp), \
    (__attribute__((address_space(3))) unsigned int*)(lp), 16, 0, 0)

// ---------------- weight transpose + bf16 convert: Wt[n][k] = bf16(W[k][n]) ----
__global__ __launch_bounds__(256) void wtrans(const float* __restrict__ W,
                                              unsigned short* __restrict__ Wt) {
    __shared__ float tile[64][65];
    const int t = threadIdx.x;
    const int tk = blockIdx.x / 12, tn = blockIdx.x % 12;
    const int k0 = tk * 64, n0 = tn * 64;
#pragma unroll
    for (int i = 0; i < 4; ++i) {
        int uid = t + 256 * i;
        int r = uid >> 4, c = (uid & 15) * 4;
        float4 v4 = *reinterpret_cast<const float4*>(W + (size_t)(k0 + r) * DH + n0 + c);
        tile[r][c] = v4.x; tile[r][c + 1] = v4.y; tile[r][c + 2] = v4.z; tile[r][c + 3] = v4.w;
    }
    __syncthreads();
#pragma unroll
    for (int i = 0; i < 2; ++i) {
        int uid = t + 256 * i;
        int n = uid >> 3, c = (uid & 7) * 8;
        union { unsigned short us[8]; uint4 u; } pk;
#pragma unroll
        for (int j = 0; j < 8; ++j) pk.us[j] = f2b(tile[c + j][n]);
        *reinterpret_cast<uint4*>(Wt + (size_t)(n0 + n) * DH + k0 + c) = pk.u;
    }
}

// ---------------- QKV projection: Y(head-split bf16) = bf16(X fp32) @ Wt^T ----
__global__ __launch_bounds__(256) void proj_qkv(const float* __restrict__ X,
                                                const unsigned short* __restrict__ Wt,
                                                unsigned short* __restrict__ Y) {
    __shared__ unsigned short As[128][40];
    __shared__ unsigned short Bs[64][40];
    const int t = threadIdx.x;
    const int w = t >> 6, lane = t & 63, lr = lane & 15, lg = lane >> 4;
    const int row0 = blockIdx.x * 128;
    const int h = blockIdx.y;
    const int n0 = h * 64;
    f32x4 acc[2][4] = {};
    for (int kt = 0; kt < 24; ++kt) {
        const int k0 = kt * 32;
#pragma unroll
        for (int i = 0; i < 4; ++i) {
            int r = (t >> 3) + 32 * i;
            int c = (t & 7) * 4;
            float4 v4 = *reinterpret_cast<const float4*>(X + (size_t)(row0 + r) * DH + k0 + c);
            uint2 pk;
            pk.x = (unsigned)f2b(v4.x) | ((unsigned)f2b(v4.y) << 16);
            pk.y = (unsigned)f2b(v4.z) | ((unsigned)f2b(v4.w) << 16);
            *reinterpret_cast<uint2*>(&As[r][c]) = pk;
        }
        {
            int n = t >> 2, c = (t & 3) * 8;
            *reinterpret_cast<uint4*>(&Bs[n][c]) =
                *reinterpret_cast<const uint4*>(Wt + (size_t)(n0 + n) * DH + k0 + c);
        }
        __syncthreads();
        short8 af[2], bf[4];
#pragma unroll
        for (int mi = 0; mi < 2; ++mi)
            af[mi] = *reinterpret_cast<const short8*>(&As[w * 32 + mi * 16 + lr][lg * 8]);
#pragma unroll
        for (int ni = 0; ni < 4; ++ni)
            bf[ni] = *reinterpret_cast<const short8*>(&Bs[ni * 16 + lr][lg * 8]);
#pragma unroll
        for (int mi = 0; mi < 2; ++mi)
#pragma unroll
            for (int ni = 0; ni < 4; ++ni)
                acc[mi][ni] = __builtin_amdgcn_mfma_f32_16x16x32_bf16(af[mi], bf[ni], acc[mi][ni], 0, 0, 0);
        __syncthreads();
    }
#pragma unroll
    for (int mi = 0; mi < 2; ++mi)
#pragma unroll
        for (int ni = 0; ni < 4; ++ni)
#pragma unroll
            for (int r = 0; r < 4; ++r) {
                int row = row0 + w * 32 + mi * 16 + lg * 4 + r;
                int b = row >> 12, s = row & 4095;
                int d = ni * 16 + lr;
                Y[(size_t)((b * NHEAD + h) * SLEN + s) * DA + d] = f2b(acc[mi][ni][r]);
            }
}

// ---------------- V transpose: VhT[bh][d][s] = Vh[bh][s][d] ----
__global__ __launch_bounds__(256) void vtrans(const unsigned short* __restrict__ Vh,
                                              unsigned short* __restrict__ VhT) {
    __shared__ unsigned short tile[64][66];
    const int t = threadIdx.x;
    const int s0 = blockIdx.x * 64;
    const int bh = blockIdx.y;
    const size_t ibase = (size_t)bh * SLEN * DA;
#pragma unroll
    for (int i = 0; i < 2; ++i) {
        int uid = t + 256 * i;
        int r = uid >> 3, c = (uid & 7) * 8;
        uint4 v = *reinterpret_cast<const uint4*>(Vh + ibase + (size_t)(s0 + r) * DA + c);
        unsigned vv[4] = {v.x, v.y, v.z, v.w};
#pragma unroll
        for (int q = 0; q < 4; ++q)
            *reinterpret_cast<unsigned*>(&tile[r][c + q * 2]) = vv[q];
    }
    __syncthreads();
#pragma unroll
    for (int i = 0; i < 2; ++i) {
        int uid = t + 256 * i;
        int d = uid >> 3, sc = uid & 7;
        union { unsigned short us[8]; uint4 u; } pk;
#pragma unroll
        for (int jj = 0; jj < 8; ++jj) pk.us[jj] = tile[sc * 8 + jj][d];
        *reinterpret_cast<uint4*>(VhT + (size_t)(bh * DA + d) * SLEN + s0 + sc * 8) = pk.u;
    }
}

// ---------------- flash attention (swapped-QK^T, in-register softmax) ----
__global__ __launch_bounds__(256, 3) void attn_kernel(const unsigned short* __restrict__ Qh,
                                                      const unsigned short* __restrict__ Kh,
                                                      const unsigned short* __restrict__ VhT,
                                                      const int* __restrict__ mask,
                                                      unsigned short* __restrict__ AT) {
    __shared__ unsigned smem4[4608];   // 18432 B: stage {Ks 8K, Vt 8K, bias 256B} / epi Ob
    unsigned short (*Ks)[64] = reinterpret_cast<unsigned short(*)[64]>(smem4);
    unsigned short (*Vt)[64] = reinterpret_cast<unsigned short(*)[64]>(smem4 + 2048);
    float* biasb = reinterpret_cast<float*>(smem4 + 4096);

    const int t = threadIdx.x;
    const int w = t >> 6, lane = t & 63, lr = lane & 15, lg = lane >> 4;
    const int g0 = lg & 1, g1 = lg >> 1;

    // bijective XCD swizzle: all 32 q-blocks of a head on one XCD (3 heads/XCD L2-resident)
    const int i = blockIdx.x;          // 0..767
    const int bh = (i & 7) * 3 + ((i >> 3) >> 5);
    const int qb = (i >> 3) & 31;
    const int b = bh / NHEAD, h = bh % NHEAD;
    const int q0 = qb * 128;
    const size_t base = (size_t)bh * SLEN * DA;
    const int wq0 = q0 + w * 32;

    short8 qf[2][2];
#pragma unroll
    for (int mi = 0; mi < 2; ++mi)
#pragma unroll
        for (int ks = 0; ks < 2; ++ks)
            qf[mi][ks] = *reinterpret_cast<const short8*>(
                Qh + base + (size_t)(wq0 + mi * 16 + lr) * DA + ks * 32 + lg * 8);

    float m_[2] = {-1e30f, -1e30f};
    float l_[2] = {0.f, 0.f};
    f32x4 oacc[2][4] = {};

    for (int kt = 0; kt < 64; ++kt) {
        const int kk0 = kt * 64;
        __syncthreads();
        // stage K,V via global_load_lds w=16; linear LDS dest, XOR-swizzled global source (pattern 21)
#pragma unroll
        for (int n = 0; n < 2; ++n) {
            int uid = ((n * 4 + w) << 6) | lane;
            int r = uid >> 3, cc = uid & 7;
            int sc = (cc ^ (r & 7)) * 8;
            GLD_LDS16(Kh + base + (size_t)(kk0 + r) * DA + sc,
                      (char*)smem4 + (n * 4 + w) * 1024);
            GLD_LDS16(VhT + (size_t)(bh * DA + r) * SLEN + kk0 + sc,
                      (char*)smem4 + 8192 + (n * 4 + w) * 1024);
        }
        if (t < 64) biasb[t] = -1e9f * (float)mask[b * SLEN + kk0 + t];
        __syncthreads();

        // bias per-lane (keys ni*16+lg*4+rr), b128 broadcast
        f32x4 bias4[4];
#pragma unroll
        for (int ni = 0; ni < 4; ++ni)
            bias4[ni] = *reinterpret_cast<const f32x4*>(&biasb[ni * 16 + lg * 4]);

        // S^T = K Q^T : out col = q(=lr), row = key
        f32x4 st[2][4] = {};
#pragma unroll
        for (int ks = 0; ks < 2; ++ks)
#pragma unroll
            for (int ni = 0; ni < 4; ++ni) {
                int row = ni * 16 + lr;
                int slot = (ks * 4 + lg) ^ (lr & 7);
                short8 kf = *reinterpret_cast<const short8*>(&Ks[row][slot * 8]);
                st[0][ni] = __builtin_amdgcn_mfma_f32_16x16x32_bf16(kf, qf[0][ks], st[0][ni], 0, 0, 0);
                st[1][ni] = __builtin_amdgcn_mfma_f32_16x16x32_bf16(kf, qf[1][ks], st[1][ni], 0, 0, 0);
            }

        float rmax[2];
#pragma unroll
        for (int mi = 0; mi < 2; ++mi) {
#pragma unroll
            for (int ni = 0; ni < 4; ++ni)
                st[mi][ni] = st[mi][ni] * 0.125f + bias4[ni];
            float v = -1e30f;
#pragma unroll
            for (int ni = 0; ni < 4; ++ni)
#pragma unroll
                for (int rr = 0; rr < 4; ++rr) v = fmaxf(v, st[mi][ni][rr]);
            v = fmaxf(v, __shfl_xor(v, 16));
            v = fmaxf(v, __shfl_xor(v, 32));
            rmax[mi] = v;
        }
        // defer-max (T13, THR=8)
        bool need = (rmax[0] > m_[0] + 8.f) || (rmax[1] > m_[1] + 8.f);
        if (__any(need)) {
#pragma unroll
            for (int mi = 0; mi < 2; ++mi) {
                float mn = fmaxf(m_[mi], rmax[mi]);
                float sc = __expf(m_[mi] - mn);
                m_[mi] = mn;
                l_[mi] *= sc;
#pragma unroll
                for (int ni = 0; ni < 4; ++ni) oacc[mi][ni] *= sc;
            }
        }

#pragma unroll
        for (int mi = 0; mi < 2; ++mi) {
            // P = exp(S - m); lane-local l partial
            unsigned D[8];
            float lsum = 0.f;
#pragma unroll
            for (int ni = 0; ni < 4; ++ni) {
                float p0 = __expf(st[mi][ni][0] - m_[mi]);
                float p1 = __expf(st[mi][ni][1] - m_[mi]);
                float p2 = __expf(st[mi][ni][2] - m_[mi]);
                float p3 = __expf(st[mi][ni][3] - m_[mi]);
                lsum += (p0 + p1) + (p2 + p3);
                D[ni * 2]     = pkbf(p0, p1);
                D[ni * 2 + 1] = pkbf(p2, p3);
            }
            l_[mi] += lsum;

            // in-register 4-lane transpose: D{p1=g0,p2=g1} -> F{p2=g0,p3=g1}
            unsigned E[8], F[8];
#pragma unroll
            for (int p4 = 0; p4 < 2; ++p4)
#pragma unroll
                for (int p0b = 0; p0b < 2; ++p0b) {
                    unsigned dlo = D[4 * p4 + p0b], dhi = D[4 * p4 + 2 + p0b];
                    unsigned own  = g1 ? dhi : dlo;
                    unsigned send = g1 ? dlo : dhi;
                    unsigned recv = __shfl_xor(send, 32);
                    E[4 * p4 + 2 + p0b] = g1 ? own : recv;
                    E[4 * p4 + p0b]     = g1 ? recv : own;
                }
#pragma unroll
            for (int p4 = 0; p4 < 2; ++p4)
#pragma unroll
                for (int p0b = 0; p0b < 2; ++p0b) {
                    unsigned elo = E[4 * p4 + p0b], ehi = E[4 * p4 + 2 + p0b];
                    unsigned own  = g0 ? ehi : elo;
                    unsigned send = g0 ? elo : ehi;
                    unsigned recv = __shfl_xor(send, 16);
                    F[4 * p4 + 2 + p0b] = g0 ? own : recv;
                    F[4 * p4 + p0b]     = g0 ? recv : own;
                }
            union { unsigned u[4]; short8 s; } pa0, pa1;
            pa0.u[0] = F[0]; pa0.u[1] = F[1]; pa0.u[2] = F[2]; pa0.u[3] = F[3];
            pa1.u[0] = F[4]; pa1.u[1] = F[5]; pa1.u[2] = F[6]; pa1.u[3] = F[7];

            // O^T += V^T P^T : out col = q(=lr), row = d
#pragma unroll
            for (int ni = 0; ni < 4; ++ni) {
                int row = ni * 16 + lr;
                int slot0 = (0 * 4 + lg) ^ (lr & 7);
                int slot1 = (1 * 4 + lg) ^ (lr & 7);
                short8 vf0 = *reinterpret_cast<const short8*>(&Vt[row][slot0 * 8]);
                short8 vf1 = *reinterpret_cast<const short8*>(&Vt[row][slot1 * 8]);
                oacc[mi][ni] = __builtin_amdgcn_mfma_f32_16x16x32_bf16(vf0, pa0.s, oacc[mi][ni], 0, 0, 0);
                oacc[mi][ni] = __builtin_amdgcn_mfma_f32_16x16x32_bf16(vf1, pa1.s, oacc[mi][ni], 0, 0, 0);
            }
        }
    }

    // epilogue: finish l, write O^T to LDS bounce, read back row-major, store coalesced
    float inv[2];
#pragma unroll
    for (int mi = 0; mi < 2; ++mi) {
        float l = l_[mi];
        l += __shfl_xor(l, 16);
        l += __shfl_xor(l, 32);
        inv[mi] = 1.0f / l;
    }
    __syncthreads();
    unsigned* Obw = smem4 + w * 32 * 36;
#pragma unroll
    for (int mi = 0; mi < 2; ++mi)
#pragma unroll
        for (int ni = 0; ni < 4; ++ni) {
            uint2 pr;
            pr.x = pkbf(oacc[mi][ni][0] * inv[mi], oacc[mi][ni][1] * inv[mi]);
            pr.y = pkbf(oacc[mi][ni][2] * inv[mi], oacc[mi][ni][3] * inv[mi]);
            *reinterpret_cast<uint2*>(&Obw[(mi * 16 + lr) * 36 + ni * 8 + lg * 2]) = pr;
        }
    __syncthreads();
    {
        int row = lane >> 1, half = lane & 1;
        int qg = q0 + w * 32 + row;
        unsigned short* dst = AT + (size_t)(b * SLEN + qg) * DH + h * DA + half * 32;
#pragma unroll
        for (int c = 0; c < 4; ++c) {
            uint4 v = *reinterpret_cast<const uint4*>(&Obw[row * 36 + half * 16 + c * 4]);
            *reinterpret_cast<uint4*>(dst + c * 8) = v;
        }
    }
}

// ---------------- output projection: out(fp32) = AT(bf16) @ Wt_o^T + b_o ----
__global__ __launch_bounds__(256) void proj_out(const unsigned short* __restrict__ X,
                                                const unsigned short* __restrict__ Wt,
                                                const float* __restrict__ bias,
                                                float* __restrict__ Y) {
    __shared__ unsigned short As[128][40];
    __shared__ unsigned short Bs[64][40];
    const int t = threadIdx.x;
    const int w = t >> 6, lane = t & 63, lr = lane & 15, lg = lane >> 4;
    const int row0 = blockIdx.x * 128;
    const int n0 = blockIdx.y * 64;
    f32x4 acc[2][4] = {};
    for (int kt = 0; kt < 24; ++kt) {
        const int k0 = kt * 32;
#pragma unroll
        for (int i = 0; i < 2; ++i) {
            int uid = t + 256 * i;
            int r = uid >> 2, c = (uid & 3) * 8;
            *reinterpret_cast<uint4*>(&As[r][c]) =
                *reinterpret_cast<const uint4*>(X + (size_t)(row0 + r) * DH + k0 + c);
        }
        {
            int n = t >> 2, c = (t & 3) * 8;
            *reinterpret_cast<uint4*>(&Bs[n][c]) =
                *reinterpret_cast<const uint4*>(Wt + (size_t)(n0 + n) * DH + k0 + c);
        }
        __syncthreads();
        short8 af[2], bf[4];
#pragma unroll
        for (int mi = 0; mi < 2; ++mi)
            af[mi] = *reinterpret_cast<const short8*>(&As[w * 32 + mi * 16 + lr][lg * 8]);
#pragma unroll
        for (int ni = 0; ni < 4; ++ni)
            bf[ni] = *reinterpret_cast<const short8*>(&Bs[ni * 16 + lr][lg * 8]);
#pragma unroll
        for (int mi = 0; mi < 2; ++mi)
#pragma unroll
            for (int ni = 0; ni < 4; ++ni)
                acc[mi][ni] = __builtin_amdgcn_mfma_f32_16x16x32_bf16(af[mi], bf[ni], acc[mi][ni], 0, 0, 0);
        __syncthreads();
    }
#pragma unroll
    for (int ni = 0; ni < 4; ++ni) {
        float bv = bias[n0 + ni * 16 + lr];
#pragma unroll
        for (int mi = 0; mi < 2; ++mi)
#pragma unroll
            for (int r = 0; r < 4; ++r) {
                int row = row0 + w * 32 + mi * 16 + lg * 4 + r;
                Y[(size_t)row * DH + n0 + ni * 16 + lr] = acc[mi][ni][r] + bv;
            }
    }
}

extern "C" void kernel_launch(void* const* d_in, const int* in_sizes, int n_in,
                              void* d_out, int out_size, void* d_ws, size_t ws_size,
                              hipStream_t stream) {
    const float* v   = (const float*)d_in[0];
    const float* k   = (const float*)d_in[1];
    const float* q   = (const float*)d_in[2];
    const int*  mask = (const int*)d_in[3];
    const float* w_v = (const float*)d_in[4];
    const float* w_k = (const float*)d_in[5];
    const float* w_q = (const float*)d_in[6];
    const float* w_o = (const float*)d_in[7];
    const float* b_o = (const float*)d_in[8];
    float* out = (float*)d_out;

    char* ws = (char*)d_ws;
    unsigned short* Qh  = (unsigned short*)(ws);                 // 12.58 MB
    unsigned short* Kh  = (unsigned short*)(ws + 12582912);
    unsigned short* Vh  = (unsigned short*)(ws + 25165824);      // dead after vtrans -> reused as AT
    unsigned short* VhT = (unsigned short*)(ws + 37748736);
    unsigned short* AT  = Vh;
    unsigned short* WtV = (unsigned short*)(ws + 50331648);
    unsigned short* WtK = WtV + 589824;
    unsigned short* WtQ = WtK + 589824;
    unsigned short* WtO = WtQ + 589824;

    wtrans<<<144, 256, 0, stream>>>(w_v, WtV);
    wtrans<<<144, 256, 0, stream>>>(w_k, WtK);
    wtrans<<<144, 256, 0, stream>>>(w_q, WtQ);
    wtrans<<<144, 256, 0, stream>>>(w_o, WtO);
    proj_qkv<<<dim3(64, 12), 256, 0, stream>>>(v, WtV, Vh);
    proj_qkv<<<dim3(64, 12), 256, 0, stream>>>(k, WtK, Kh);
    proj_qkv<<<dim3(64, 12), 256, 0, stream>>>(q, WtQ, Qh);
    vtrans<<<dim3(64, 24), 256, 0, stream>>>(Vh, VhT);
    attn_kernel<<<768, 256, 0, stream>>>(Qh, Kh, VhT, mask, AT);
    proj_out<<<dim3(64, 12), 256, 0, stream>>>(AT, WtO, b_o, out);
}

// Round 3
// 264.349 us; speedup vs baseline: 2.2086x; 1.1146x over previous
//
#include <hip/hip_runtime.h>
#include <hip/hip_bf16.h>

#define SLEN 4096
#define DH 768
#define NHEAD 12
#define DA 64

using short8 = __attribute__((ext_vector_type(8))) short;
using f32x4  = __attribute__((ext_vector_type(4))) float;

static __device__ __forceinline__ unsigned short f2b(float f) {
    union { float f; unsigned u; } x; x.f = f;
    unsigned r = (x.u + 0x7FFFu + ((x.u >> 16) & 1)) >> 16;
    return (unsigned short)r;
}

static __device__ __forceinline__ unsigned pkbf(float a, float b) {
    __hip_bfloat162 h = __float22bfloat162_rn(float2{a, b});
    union { __hip_bfloat162 h; unsigned u; } c; c.h = h; return c.u;
}

static __device__ __forceinline__ float fexp2(float x) {
#if __has_builtin(__builtin_amdgcn_exp2f)
    return __builtin_amdgcn_exp2f(x);
#else
    return exp2f(x);
#endif
}

// {a,b} -> a'={a.lo,b.lo}, b'={a.hi,b.hi}  (swap across lane^32)
static __device__ __forceinline__ void swap32(unsigned& a, unsigned& b, int g1) {
#if __has_builtin(__builtin_amdgcn_permlane32_swap)
    typedef unsigned uv2 __attribute__((ext_vector_type(2)));
    uv2 r = __builtin_amdgcn_permlane32_swap(a, b, false, false);
    a = r.x; b = r.y;
#else
    unsigned own = g1 ? b : a, send = g1 ? a : b;
    unsigned recv = __shfl_xor(send, 32);
    unsigned nlo = g1 ? recv : own;
    unsigned nhi = g1 ? own : recv;
    a = nlo; b = nhi;
#endif
}

// {a,b} -> a'={a.q0,b.q0,a.q2,b.q2}, b'={a.q1,b.q1,a.q3,b.q3}  (swap across lane^16)
static __device__ __forceinline__ void swap16(unsigned& a, unsigned& b, int g0) {
#if __has_builtin(__builtin_amdgcn_permlane16_swap)
    typedef unsigned uv2 __attribute__((ext_vector_type(2)));
    uv2 r = __builtin_amdgcn_permlane16_swap(a, b, false, false);
    a = r.x; b = r.y;
#else
    unsigned own = g0 ? b : a, send = g0 ? a : b;
    unsigned recv = __shfl_xor(send, 16);
    unsigned nlo = g0 ? recv : own;
    unsigned nhi = g0 ? own : recv;
    a = nlo; b = nhi;
#endif
}

#define GLD_LDS16(gp, lp) __builtin_amdgcn_global_load_lds( \
    (const __attribute__((address_space(1))) unsigned int*)(gp), \
    (__attribute__((address_space(3))) unsigned int*)(lp), 16, 0, 0)

// ------- merged: 4x weight transpose+cvt, plus mask -> log2-domain bias expand -------
__global__ __launch_bounds__(256) void wtrans4(const float* __restrict__ w_v, const float* __restrict__ w_k,
                                               const float* __restrict__ w_q, const float* __restrict__ w_o,
                                               unsigned short* __restrict__ WtV, unsigned short* __restrict__ WtK,
                                               unsigned short* __restrict__ WtQ, unsigned short* __restrict__ WtO,
                                               const int* __restrict__ mask, float* __restrict__ biasE) {
    const int z = blockIdx.y;
    const int t = threadIdx.x;
    if (z == 4) {
        int i = blockIdx.x * 256 + t;
        if (i < 2 * SLEN) biasE[i] = -1.442695041e9f * (float)mask[i];
        return;
    }
    const float* W = (z == 0) ? w_v : (z == 1) ? w_k : (z == 2) ? w_q : w_o;
    unsigned short* Wt = (z == 0) ? WtV : (z == 1) ? WtK : (z == 2) ? WtQ : WtO;
    __shared__ float tile[64][65];
    const int tk = blockIdx.x / 12, tn = blockIdx.x % 12;
    const int k0 = tk * 64, n0 = tn * 64;
#pragma unroll
    for (int i = 0; i < 4; ++i) {
        int uid = t + 256 * i;
        int r = uid >> 4, c = (uid & 15) * 4;
        float4 v4 = *reinterpret_cast<const float4*>(W + (size_t)(k0 + r) * DH + n0 + c);
        tile[r][c] = v4.x; tile[r][c + 1] = v4.y; tile[r][c + 2] = v4.z; tile[r][c + 3] = v4.w;
    }
    __syncthreads();
#pragma unroll
    for (int i = 0; i < 2; ++i) {
        int uid = t + 256 * i;
        int n = uid >> 3, c = (uid & 7) * 8;
        union { unsigned short us[8]; uint4 u; } pk;
#pragma unroll
        for (int j = 0; j < 8; ++j) pk.us[j] = f2b(tile[c + j][n]);
        *reinterpret_cast<uint4*>(Wt + (size_t)(n0 + n) * DH + k0 + c) = pk.u;
    }
}

// ---------------- QKV projection: Y(head-split bf16) = bf16(X fp32) @ Wt^T ----
__global__ __launch_bounds__(256) void proj_qkv(const float* __restrict__ X,
                                                const unsigned short* __restrict__ Wt,
                                                unsigned short* __restrict__ Y) {
    __shared__ unsigned short As[128][40];
    __shared__ unsigned short Bs[64][40];
    const int t = threadIdx.x;
    const int w = t >> 6, lane = t & 63, lr = lane & 15, lg = lane >> 4;
    const int row0 = blockIdx.x * 128;
    const int h = blockIdx.y;
    const int n0 = h * 64;
    f32x4 acc[2][4] = {};
    for (int kt = 0; kt < 24; ++kt) {
        const int k0 = kt * 32;
#pragma unroll
        for (int i = 0; i < 4; ++i) {
            int r = (t >> 3) + 32 * i;
            int c = (t & 7) * 4;
            float4 v4 = *reinterpret_cast<const float4*>(X + (size_t)(row0 + r) * DH + k0 + c);
            uint2 pk;
            pk.x = (unsigned)f2b(v4.x) | ((unsigned)f2b(v4.y) << 16);
            pk.y = (unsigned)f2b(v4.z) | ((unsigned)f2b(v4.w) << 16);
            *reinterpret_cast<uint2*>(&As[r][c]) = pk;
        }
        {
            int n = t >> 2, c = (t & 3) * 8;
            *reinterpret_cast<uint4*>(&Bs[n][c]) =
                *reinterpret_cast<const uint4*>(Wt + (size_t)(n0 + n) * DH + k0 + c);
        }
        __syncthreads();
        short8 af[2], bf[4];
#pragma unroll
        for (int mi = 0; mi < 2; ++mi)
            af[mi] = *reinterpret_cast<const short8*>(&As[w * 32 + mi * 16 + lr][lg * 8]);
#pragma unroll
        for (int ni = 0; ni < 4; ++ni)
            bf[ni] = *reinterpret_cast<const short8*>(&Bs[ni * 16 + lr][lg * 8]);
#pragma unroll
        for (int mi = 0; mi < 2; ++mi)
#pragma unroll
            for (int ni = 0; ni < 4; ++ni)
                acc[mi][ni] = __builtin_amdgcn_mfma_f32_16x16x32_bf16(af[mi], bf[ni], acc[mi][ni], 0, 0, 0);
        __syncthreads();
    }
#pragma unroll
    for (int mi = 0; mi < 2; ++mi)
#pragma unroll
        for (int ni = 0; ni < 4; ++ni)
#pragma unroll
            for (int r = 0; r < 4; ++r) {
                int row = row0 + w * 32 + mi * 16 + lg * 4 + r;
                int b = row >> 12, s = row & 4095;
                int d = ni * 16 + lr;
                Y[(size_t)((b * NHEAD + h) * SLEN + s) * DA + d] = f2b(acc[mi][ni][r]);
            }
}

// ---------------- V transpose: VhT[bh][d][s] = Vh[bh][s][d] ----
__global__ __launch_bounds__(256) void vtrans(const unsigned short* __restrict__ Vh,
                                              unsigned short* __restrict__ VhT) {
    __shared__ unsigned short tile[64][66];
    const int t = threadIdx.x;
    const int s0 = blockIdx.x * 64;
    const int bh = blockIdx.y;
    const size_t ibase = (size_t)bh * SLEN * DA;
#pragma unroll
    for (int i = 0; i < 2; ++i) {
        int uid = t + 256 * i;
        int r = uid >> 3, c = (uid & 7) * 8;
        uint4 v = *reinterpret_cast<const uint4*>(Vh + ibase + (size_t)(s0 + r) * DA + c);
        unsigned vv[4] = {v.x, v.y, v.z, v.w};
#pragma unroll
        for (int q = 0; q < 4; ++q)
            *reinterpret_cast<unsigned*>(&tile[r][c + q * 2]) = vv[q];
    }
    __syncthreads();
#pragma unroll
    for (int i = 0; i < 2; ++i) {
        int uid = t + 256 * i;
        int d = uid >> 3, sc = uid & 7;
        union { unsigned short us[8]; uint4 u; } pk;
#pragma unroll
        for (int jj = 0; jj < 8; ++jj) pk.us[jj] = tile[sc * 8 + jj][d];
        *reinterpret_cast<uint4*>(VhT + (size_t)(bh * DA + d) * SLEN + s0 + sc * 8) = pk.u;
    }
}

// ---------------- flash attention (swapped-QK^T, exp2 domain, dbuf staging) ----
__global__ __launch_bounds__(256, 3) void attn_kernel(const unsigned short* __restrict__ Qh,
                                                      const unsigned short* __restrict__ Kh,
                                                      const unsigned short* __restrict__ VhT,
                                                      const float* __restrict__ biasE,
                                                      unsigned short* __restrict__ AT) {
    __shared__ unsigned smem4[8192];   // 32 KB: [K0 8K][V0 8K][K1 8K][V1 8K]; epilogue reuse

    const int t = threadIdx.x;
    const int w = t >> 6, lane = t & 63, lr = lane & 15, lg = lane >> 4;
    const int g0 = (lane >> 4) & 1, g1 = (lane >> 5) & 1;
    const int lr7 = lr & 7;

    // bijective XCD swizzle: 3 heads per XCD, all 32 q-blocks of a head on one XCD
    const int i = blockIdx.x;          // 0..767
    const int bh = (i & 7) * 3 + ((i >> 3) >> 5);
    const int qb = (i >> 3) & 31;
    const int b = bh / NHEAD;
    const int q0 = qb * 128;
    const size_t base = (size_t)bh * SLEN * DA;
    const int wq0 = q0 + w * 32;

    short8 qf[2][2];
#pragma unroll
    for (int mi = 0; mi < 2; ++mi)
#pragma unroll
        for (int ks = 0; ks < 2; ++ks)
            qf[mi][ks] = *reinterpret_cast<const short8*>(
                Qh + base + (size_t)(wq0 + mi * 16 + lr) * DA + ks * 32 + lg * 8);

    // lane-constant staging offsets (linear LDS dest, XOR-pre-swizzled global source)
    const int uid0 = (w << 6) | lane, uid1 = ((4 + w) << 6) | lane;
    const int r0 = uid0 >> 3, r1 = uid1 >> 3;
    const int sc0 = ((uid0 & 7) ^ (r0 & 7)) * 8, sc1 = ((uid1 & 7) ^ (r1 & 7)) * 8;
    const size_t kofs0 = base + (size_t)r0 * DA + sc0;
    const size_t kofs1 = base + (size_t)r1 * DA + sc1;
    const size_t vofs0 = ((size_t)bh * DA + r0) * SLEN + sc0;
    const size_t vofs1 = ((size_t)bh * DA + r1) * SLEN + sc1;
    const float* biasB = biasE + b * SLEN;

#define STAGE(KT, PAR) do {                                                         \
        size_t koff_ = (size_t)(KT) * 64 * DA; int vcol_ = (KT) * 64;               \
        char* lb_ = (char*)smem4 + (PAR) * 16384;                                   \
        GLD_LDS16(Kh + kofs0 + koff_, lb_ + w * 1024);                              \
        GLD_LDS16(Kh + kofs1 + koff_, lb_ + (4 + w) * 1024);                        \
        GLD_LDS16(VhT + vofs0 + vcol_, lb_ + 8192 + w * 1024);                      \
        GLD_LDS16(VhT + vofs1 + vcol_, lb_ + 8192 + (4 + w) * 1024);                \
    } while (0)

    float m_[2] = {-1e30f, -1e30f};
    float l_[2] = {0.f, 0.f};
    f32x4 oacc[2][4] = {};
    const float C = 0.18033688011f;    // 0.125 * log2(e)

    STAGE(0, 0);
    __syncthreads();

    for (int kt = 0; kt < 64; ++kt) {
        const int par = kt & 1;
        const int kk0 = kt * 64;
        if (kt < 63) STAGE(kt + 1, par ^ 1);

        const unsigned short (*Ks)[64] =
            (const unsigned short(*)[64])((const char*)smem4 + par * 16384);
        const unsigned short (*Vt)[64] =
            (const unsigned short(*)[64])((const char*)smem4 + par * 16384 + 8192);

        f32x4 bias4[4];
#pragma unroll
        for (int ni = 0; ni < 4; ++ni)
            bias4[ni] = *reinterpret_cast<const f32x4*>(biasB + kk0 + ni * 16 + lg * 4);

        // S^T = K Q^T : out col = q(=lr), row = key
        f32x4 st[2][4] = {};
        __builtin_amdgcn_s_setprio(1);
#pragma unroll
        for (int ks = 0; ks < 2; ++ks)
#pragma unroll
            for (int ni = 0; ni < 4; ++ni) {
                int slot = (ks * 4 + lg) ^ lr7;
                short8 kf = *reinterpret_cast<const short8*>(&Ks[ni * 16 + lr][slot * 8]);
                st[0][ni] = __builtin_amdgcn_mfma_f32_16x16x32_bf16(kf, qf[0][ks], st[0][ni], 0, 0, 0);
                st[1][ni] = __builtin_amdgcn_mfma_f32_16x16x32_bf16(kf, qf[1][ks], st[1][ni], 0, 0, 0);
            }
        __builtin_amdgcn_s_setprio(0);

        float rmax[2];
#pragma unroll
        for (int mi = 0; mi < 2; ++mi) {
#pragma unroll
            for (int ni = 0; ni < 4; ++ni)
                st[mi][ni] = st[mi][ni] * C + bias4[ni];
            float v0 = fmaxf(fmaxf(st[mi][0][0], st[mi][0][1]), fmaxf(st[mi][0][2], st[mi][0][3]));
            float v1 = fmaxf(fmaxf(st[mi][1][0], st[mi][1][1]), fmaxf(st[mi][1][2], st[mi][1][3]));
            float v2 = fmaxf(fmaxf(st[mi][2][0], st[mi][2][1]), fmaxf(st[mi][2][2], st[mi][2][3]));
            float v3 = fmaxf(fmaxf(st[mi][3][0], st[mi][3][1]), fmaxf(st[mi][3][2], st[mi][3][3]));
            float v = fmaxf(fmaxf(v0, v1), fmaxf(v2, v3));
            v = fmaxf(v, __shfl_xor(v, 16));
            v = fmaxf(v, __shfl_xor(v, 32));
            rmax[mi] = v;
        }
        // defer-max (T13): skip O/l rescale while tile max stays within 2^8 of running max
        bool need = (rmax[0] > m_[0] + 8.f) || (rmax[1] > m_[1] + 8.f);
        if (__any(need)) {
#pragma unroll
            for (int mi = 0; mi < 2; ++mi) {
                float mn = fmaxf(m_[mi], rmax[mi]);
                float sc = fexp2(m_[mi] - mn);
                m_[mi] = mn;
                l_[mi] *= sc;
#pragma unroll
                for (int ni = 0; ni < 4; ++ni) oacc[mi][ni] *= sc;
            }
        }

#pragma unroll
        for (int mi = 0; mi < 2; ++mi) {
            unsigned D[8];
            float lsum = 0.f;
#pragma unroll
            for (int ni = 0; ni < 4; ++ni) {
                float p0 = fexp2(st[mi][ni][0] - m_[mi]);
                float p1 = fexp2(st[mi][ni][1] - m_[mi]);
                float p2 = fexp2(st[mi][ni][2] - m_[mi]);
                float p3 = fexp2(st[mi][ni][3] - m_[mi]);
                lsum += (p0 + p1) + (p2 + p3);
                D[ni * 2]     = pkbf(p0, p1);
                D[ni * 2 + 1] = pkbf(p2, p3);
            }
            l_[mi] += lsum;

            // in-register P transpose via permlane swaps (T12)
#pragma unroll
            for (int p4 = 0; p4 < 2; ++p4)
#pragma unroll
                for (int p0b = 0; p0b < 2; ++p0b)
                    swap32(D[4 * p4 + p0b], D[4 * p4 + 2 + p0b], g1);
#pragma unroll
            for (int p4 = 0; p4 < 2; ++p4)
#pragma unroll
                for (int p0b = 0; p0b < 2; ++p0b)
                    swap16(D[4 * p4 + p0b], D[4 * p4 + 2 + p0b], g0);
            union { unsigned u[4]; short8 s; } pa0, pa1;
            pa0.u[0] = D[0]; pa0.u[1] = D[1]; pa0.u[2] = D[2]; pa0.u[3] = D[3];
            pa1.u[0] = D[4]; pa1.u[1] = D[5]; pa1.u[2] = D[6]; pa1.u[3] = D[7];

            // O^T += V^T P^T : out col = q(=lr), row = d
            __builtin_amdgcn_s_setprio(1);
#pragma unroll
            for (int ni = 0; ni < 4; ++ni) {
                int row = ni * 16 + lr;
                int slot0 = lg ^ lr7;
                int slot1 = (4 + lg) ^ lr7;
                short8 vf0 = *reinterpret_cast<const short8*>(&Vt[row][slot0 * 8]);
                short8 vf1 = *reinterpret_cast<const short8*>(&Vt[row][slot1 * 8]);
                oacc[mi][ni] = __builtin_amdgcn_mfma_f32_16x16x32_bf16(vf0, pa0.s, oacc[mi][ni], 0, 0, 0);
                oacc[mi][ni] = __builtin_amdgcn_mfma_f32_16x16x32_bf16(vf1, pa1.s, oacc[mi][ni], 0, 0, 0);
            }
            __builtin_amdgcn_s_setprio(0);
        }
        __syncthreads();
    }
#undef STAGE

    // epilogue: finish l, O^T -> LDS bounce -> coalesced row-major store
    float inv[2];
#pragma unroll
    for (int mi = 0; mi < 2; ++mi) {
        float l = l_[mi];
        l += __shfl_xor(l, 16);
        l += __shfl_xor(l, 32);
        inv[mi] = 1.0f / l;
    }
    unsigned* Obw = smem4 + w * 32 * 36;
#pragma unroll
    for (int mi = 0; mi < 2; ++mi)
#pragma unroll
        for (int ni = 0; ni < 4; ++ni) {
            uint2 pr;
            pr.x = pkbf(oacc[mi][ni][0] * inv[mi], oacc[mi][ni][1] * inv[mi]);
            pr.y = pkbf(oacc[mi][ni][2] * inv[mi], oacc[mi][ni][3] * inv[mi]);
            *reinterpret_cast<uint2*>(&Obw[(mi * 16 + lr) * 36 + ni * 8 + lg * 2]) = pr;
        }
    __syncthreads();
    {
        int row = lane >> 1, half = lane & 1;
        int qg = q0 + w * 32 + row;
        unsigned short* dst = AT + (size_t)(b * SLEN + qg) * DH + (bh % NHEAD) * DA + half * 32;
#pragma unroll
        for (int c = 0; c < 4; ++c) {
            uint4 v = *reinterpret_cast<const uint4*>(&Obw[row * 36 + half * 16 + c * 4]);
            *reinterpret_cast<uint4*>(dst + c * 8) = v;
        }
    }
}

// ---------------- output projection: out(fp32) = AT(bf16) @ Wt_o^T + b_o ----
__global__ __launch_bounds__(256) void proj_out(const unsigned short* __restrict__ X,
                                                const unsigned short* __restrict__ Wt,
                                                const float* __restrict__ bias,
                                                float* __restrict__ Y) {
    __shared__ unsigned short As[128][40];
    __shared__ unsigned short Bs[64][40];
    const int t = threadIdx.x;
    const int w = t >> 6, lane = t & 63, lr = lane & 15, lg = lane >> 4;
    const int row0 = blockIdx.x * 128;
    const int n0 = blockIdx.y * 64;
    f32x4 acc[2][4] = {};
    for (int kt = 0; kt < 24; ++kt) {
        const int k0 = kt * 32;
#pragma unroll
        for (int i = 0; i < 2; ++i) {
            int uid = t + 256 * i;
            int r = uid >> 2, c = (uid & 3) * 8;
            *reinterpret_cast<uint4*>(&As[r][c]) =
                *reinterpret_cast<const uint4*>(X + (size_t)(row0 + r) * DH + k0 + c);
        }
        {
            int n = t >> 2, c = (t & 3) * 8;
            *reinterpret_cast<uint4*>(&Bs[n][c]) =
                *reinterpret_cast<const uint4*>(Wt + (size_t)(n0 + n) * DH + k0 + c);
        }
        __syncthreads();
        short8 af[2], bf[4];
#pragma unroll
        for (int mi = 0; mi < 2; ++mi)
            af[mi] = *reinterpret_cast<const short8*>(&As[w * 32 + mi * 16 + lr][lg * 8]);
#pragma unroll
        for (int ni = 0; ni < 4; ++ni)
            bf[ni] = *reinterpret_cast<const short8*>(&Bs[ni * 16 + lr][lg * 8]);
#pragma unroll
        for (int mi = 0; mi < 2; ++mi)
#pragma unroll
            for (int ni = 0; ni < 4; ++ni)
                acc[mi][ni] = __builtin_amdgcn_mfma_f32_16x16x32_bf16(af[mi], bf[ni], acc[mi][ni], 0, 0, 0);
        __syncthreads();
    }
#pragma unroll
    for (int ni = 0; ni < 4; ++ni) {
        float bv = bias[n0 + ni * 16 + lr];
#pragma unroll
        for (int mi = 0; mi < 2; ++mi)
#pragma unroll
            for (int r = 0; r < 4; ++r) {
                int row = row0 + w * 32 + mi * 16 + lg * 4 + r;
                Y[(size_t)row * DH + n0 + ni * 16 + lr] = acc[mi][ni][r] + bv;
            }
    }
}

extern "C" void kernel_launch(void* const* d_in, const int* in_sizes, int n_in,
                              void* d_out, int out_size, void* d_ws, size_t ws_size,
                              hipStream_t stream) {
    const float* v   = (const float*)d_in[0];
    const float* k   = (const float*)d_in[1];
    const float* q   = (const float*)d_in[2];
    const int*  mask = (const int*)d_in[3];
    const float* w_v = (const float*)d_in[4];
    const float* w_k = (const float*)d_in[5];
    const float* w_q = (const float*)d_in[6];
    const float* w_o = (const float*)d_in[7];
    const float* b_o = (const float*)d_in[8];
    float* out = (float*)d_out;

    char* ws = (char*)d_ws;
    unsigned short* Qh  = (unsigned short*)(ws);                 // 12.58 MB
    unsigned short* Kh  = (unsigned short*)(ws + 12582912);
    unsigned short* Vh  = (unsigned short*)(ws + 25165824);      // dead after vtrans -> reused as AT
    unsigned short* VhT = (unsigned short*)(ws + 37748736);
    unsigned short* AT  = Vh;
    unsigned short* WtV = (unsigned short*)(ws + 50331648);
    unsigned short* WtK = WtV + 589824;
    unsigned short* WtQ = WtK + 589824;
    unsigned short* WtO = WtQ + 589824;
    float* biasE = (float*)(ws + 55050240);                      // 32 KB

    wtrans4<<<dim3(144, 5), 256, 0, stream>>>(w_v, w_k, w_q, w_o, WtV, WtK, WtQ, WtO, mask, biasE);
    proj_qkv<<<dim3(64, 12), 256, 0, stream>>>(v, WtV, Vh);
    proj_qkv<<<dim3(64, 12), 256, 0, stream>>>(k, WtK, Kh);
    proj_qkv<<<dim3(64, 12), 256, 0, stream>>>(q, WtQ, Qh);
    vtrans<<<dim3(64, 24), 256, 0, stream>>>(Vh, VhT);
    attn_kernel<<<768, 256, 0, stream>>>(Qh, Kh, VhT, biasE, AT);
    proj_out<<<dim3(64, 12), 256, 0, stream>>>(AT, WtO, b_o, out);
}